// Round 3
// baseline (186.624 us; speedup 1.0000x reference)
//
#include <hip/hip_runtime.h>

typedef __attribute__((ext_vector_type(8))) short short8;
typedef __attribute__((ext_vector_type(4))) float floatx4;

__device__ __forceinline__ short bf16_short(float f) {
    unsigned u = __builtin_bit_cast(unsigned, f);
    u = (u + 0x7fff + ((u >> 16) & 1)) >> 16;   // RNE, finite values only
    return (short)u;
}
__device__ __forceinline__ float bf16_to_f(short s) {
    unsigned u = ((unsigned)(unsigned short)s) << 16;
    return __builtin_bit_cast(float, u);
}

// ---------------------------------------------------------------------------
// Kernel 1: relayout weights (fp32 -> bf16) for MFMA A-fragments.
// Wt layout: [tap(9)][cog(4)][chunk(16)][co(128)][j(8)]  (ci = chunk*8+j)
// Wot layout: [chunk(16)][co(128)][j(8)]
// ---------------------------------------------------------------------------
__global__ __launch_bounds__(256) void transform_w(
    const float* __restrict__ wi, const float* __restrict__ wq,
    const float* __restrict__ wo, short* __restrict__ Wt, short* __restrict__ Wot)
{
    int idx = blockIdx.x * 256 + threadIdx.x;
    if (idx < 589824) {
        int j  = idx & 7;
        int t1 = idx >> 3;
        int co = t1 & 127;
        int t2 = t1 >> 7;
        int chunk = t2 & 15;
        int t3 = t2 >> 4;
        int cog = t3 & 3;
        int tap = t3 >> 2;
        int ci = chunk * 8 + j;
        float v;
        if (cog == 0) v = wi[(co * 128 + ci) * 9 + tap];
        else          v = wq[((((cog - 1) * 128) + co) * 128 + ci) * 9 + tap];
        Wt[idx] = bf16_short(v);
    } else if (idx < 589824 + 16384) {
        int i2 = idx - 589824;
        int j  = i2 & 7;
        int co = (i2 >> 3) & 127;
        int chunk = i2 >> 10;
        int ci = chunk * 8 + j;
        Wot[i2] = bf16_short(wo[co * 128 + ci]);
    }
}

// ---------------------------------------------------------------------------
// Kernel 2: fused circular 3x3 convs (init 128ch + qkv 384ch) as implicit GEMM.
// Block = (y-row, cog, b). M=128 (co group), N=48 (cols of row y), K=1152.
// cog==0 -> d_out (fp32) channels 0..127 ; cog 1..3 -> qkv ws bf16 (q * 0.25).
// x is fp32; converted to bf16 during LDS staging.
// ---------------------------------------------------------------------------
__global__ __launch_bounds__(256) void conv_main(
    const float* __restrict__ x, const short* __restrict__ Wt,
    float* __restrict__ dout, short* __restrict__ qkv)
{
    const int y   = blockIdx.x;   // 0..47
    const int cog = blockIdx.y;   // 0..3
    const int b   = blockIdx.z;   // 0..3

    __shared__ short Xs[16 * 3 * 48 * 8];   // [(chunk*3+row)*48+col]*8+j
    __shared__ short Ws[16 * 128 * 8];      // [chunk][co][j]

    const int t = threadIdx.x;

    // Stage X rows y-1,y,y+1 (wrapped): 128ci x 3row x 48col, fp32 -> bf16
    {
        const float* xb = x + b * 128 * 2304;
        #pragma unroll 4
        for (int it = 0; it < 36; ++it) {
            int e   = it * 256 + t;          // 0..9215 column pairs
            int ci  = e / 72;
            int r   = e - ci * 72;
            int row = r / 24;
            int cp  = r - row * 24;
            int rowg = y + row - 1;
            rowg = (rowg < 0) ? rowg + 48 : (rowg >= 48 ? rowg - 48 : rowg);
            float2 v = *(const float2*)(xb + (ci * 48 + rowg) * 48 + cp * 2);
            int slot = ((ci >> 3) * 3 + row) * 48 + cp * 2;
            int j = ci & 7;
            Xs[slot * 8 + j]       = bf16_short(v.x);
            Xs[(slot + 1) * 8 + j] = bf16_short(v.y);
        }
    }

    const int wave = t >> 6, lane = t & 63, quad = lane >> 4, l16 = lane & 15;

    floatx4 acc[2][3];
    #pragma unroll
    for (int i = 0; i < 2; ++i)
        #pragma unroll
        for (int jn = 0; jn < 3; ++jn) acc[i][jn] = (floatx4){0.f, 0.f, 0.f, 0.f};

    for (int tap = 0; tap < 9; ++tap) {
        __syncthreads();
        // stage W slab for this (tap, cog): contiguous 16384 shorts
        {
            const short8* src = (const short8*)(Wt + (tap * 4 + cog) * 16 * 128 * 8);
            short8* dst = (short8*)Ws;
            #pragma unroll
            for (int it = 0; it < 8; ++it) dst[it * 256 + t] = src[it * 256 + t];
        }
        __syncthreads();

        const int dy = tap / 3, dx = tap % 3;
        int colw[3];
        #pragma unroll
        for (int nt = 0; nt < 3; ++nt) {
            int c = nt * 16 + l16 + dx - 1;
            c = (c < 0) ? c + 48 : (c >= 48 ? c - 48 : c);
            colw[nt] = c;
        }

        #pragma unroll
        for (int kk = 0; kk < 4; ++kk) {
            int chA = kk * 4 + quad;
            short8 a0 = *(const short8*)&Ws[(chA * 128 + wave * 32 + l16) * 8];
            short8 a1 = *(const short8*)&Ws[(chA * 128 + wave * 32 + 16 + l16) * 8];
            #pragma unroll
            for (int nt = 0; nt < 3; ++nt) {
                short8 bf = *(const short8*)&Xs[((chA * 3 + dy) * 48 + colw[nt]) * 8];
                acc[0][nt] = __builtin_amdgcn_mfma_f32_16x16x32_bf16(a0, bf, acc[0][nt], 0, 0, 0);
                acc[1][nt] = __builtin_amdgcn_mfma_f32_16x16x32_bf16(a1, bf, acc[1][nt], 0, 0, 0);
            }
        }
    }

    // Epilogue: C/D layout col=l16 (spatial), row=quad*4+r (co)
    #pragma unroll
    for (int mt = 0; mt < 2; ++mt)
        #pragma unroll
        for (int nt = 0; nt < 3; ++nt)
            #pragma unroll
            for (int r = 0; r < 4; ++r) {
                int col  = nt * 16 + l16;
                int n    = y * 48 + col;
                int co_l = wave * 32 + mt * 16 + quad * 4 + r;
                float v  = acc[mt][nt][r];
                if (cog == 0) {
                    dout[(b * 256 + co_l) * 2304 + n] = v;            // fp32 out
                } else {
                    int c = (cog - 1) * 128 + co_l;
                    if (c < 128) v *= 0.25f;   // q scale dk_h^-0.5
                    qkv[(b * 384 + c) * 2304 + n] = bf16_short(v);
                }
            }
}

// ---------------------------------------------------------------------------
// Kernel 3: flash-style attention. Block = (n-tile of 64, b*8+h).
// No max subtraction (logits bounded ~ +-7). O via MFMA; row-sums accumulated
// in P A-layout domain, reduced across quads at end.
// attnbuf layout (b, h, n, d) flat == raw reshape to (b,128,2304).
// ---------------------------------------------------------------------------
__global__ __launch_bounds__(256) void attn_kernel(
    const short* __restrict__ qkv, short* __restrict__ attnbuf)
{
    const int b  = blockIdx.y >> 3, h = blockIdx.y & 7;
    const int n0 = blockIdx.x * 64;
    constexpr int RS = 40;                 // row stride (shorts), 16B-aligned rows

    __shared__ short Qs[64 * RS];          // [n][k], k 16..31 zero-padded
    __shared__ short Ks[32 * RS];          // [m][k], k 16..31 zero-padded
    __shared__ short Ps[4][16 * RS];       // per-wave P transform buffer
    __shared__ float Ls[64];

    const int t = threadIdx.x;
    const int wave = t >> 6, lane = t & 63, quad = lane >> 4, l16 = lane & 15;

    {   // zero Qs + Ks (covers the k>=16 zero padding)
        unsigned* z1 = (unsigned*)Qs;
        for (int i = t; i < 64 * RS / 2; i += 256) z1[i] = 0;
        unsigned* z2 = (unsigned*)Ks;
        for (int i = t; i < 32 * RS / 2; i += 256) z2[i] = 0;
    }
    __syncthreads();

    const short* qb = qkv + (b * 384 + h * 16) * 2304;
    const short* kb = qkv + (b * 384 + 128 + h * 16) * 2304;
    const short* vb = qkv + (b * 384 + 256 + h * 16) * 2304;

    // stage Q tile (transpose d x 64n -> [n][d])
    #pragma unroll
    for (int it = 0; it < 2; ++it) {
        int e = it * 256 + t;              // 0..511
        int d = e >> 5, np = e & 31;
        unsigned v = *(const unsigned*)(qb + d * 2304 + n0 + np * 2);
        Qs[(np * 2) * RS + d]     = (short)(v & 0xffff);
        Qs[(np * 2 + 1) * RS + d] = (short)(v >> 16);
    }

    floatx4 acc = {0.f, 0.f, 0.f, 0.f};
    float lsum = 0.f;

    for (int mi = 0; mi < 72; ++mi) {
        int m0 = mi * 32;
        __syncthreads();   // prev iter readers done with Ks (first iter: Q/zero staging)
        {   // stage K tile (transpose d x 32m -> [m][d])
            int d = t >> 4, mp = t & 15;
            unsigned v = *(const unsigned*)(kb + d * 2304 + m0 + mp * 2);
            Ks[(mp * 2) * RS + d]     = (short)(v & 0xffff);
            Ks[(mp * 2 + 1) * RS + d] = (short)(v >> 16);
        }
        __syncthreads();

        short8 aq  = *(const short8*)&Qs[(wave * 16 + l16) * RS + quad * 8];
        short8 bk0 = *(const short8*)&Ks[l16 * RS + quad * 8];
        short8 bk1 = *(const short8*)&Ks[(16 + l16) * RS + quad * 8];
        floatx4 z = {0.f, 0.f, 0.f, 0.f};
        floatx4 s0 = __builtin_amdgcn_mfma_f32_16x16x32_bf16(aq, bk0, z, 0, 0, 0);
        floatx4 s1 = __builtin_amdgcn_mfma_f32_16x16x32_bf16(aq, bk1, z, 0, 0, 0);

        // exp (no max-sub), convert to bf16, write C-layout -> A-layout via LDS
        short* pw = &Ps[wave][0];
        #pragma unroll
        for (int r = 0; r < 4; ++r) {
            float p0 = __expf(s0[r]);
            float p1 = __expf(s1[r]);
            pw[(quad * 4 + r) * RS + l16]      = bf16_short(p0);
            pw[(quad * 4 + r) * RS + 16 + l16] = bf16_short(p1);
        }
        __syncthreads();

        short8 pf = *(const short8*)&pw[l16 * RS + quad * 8];
        #pragma unroll
        for (int j = 0; j < 8; ++j) lsum += bf16_to_f(pf[j]);

        short8 vf = *(const short8*)(vb + l16 * 2304 + m0 + quad * 8);
        acc = __builtin_amdgcn_mfma_f32_16x16x32_bf16(pf, vf, acc, 0, 0, 0);
    }

    // combine quad partial row-sums (lane&15 = n within wave tile)
    lsum += __shfl_xor(lsum, 16, 64);
    lsum += __shfl_xor(lsum, 32, 64);
    Ls[wave * 16 + l16] = lsum;
    __syncthreads();

    #pragma unroll
    for (int r = 0; r < 4; ++r) {
        int nl = quad * 4 + r;
        float v = acc[r] / Ls[wave * 16 + nl];
        int n = n0 + wave * 16 + nl;
        attnbuf[((b * 8 + h) * 2304 + n) * 16 + l16] = bf16_short(v);
    }
}

// ---------------------------------------------------------------------------
// Kernel 4: 1x1 conv on raw-reshaped attention buffer. M=128, N=32, K=128.
// Writes d_out (fp32) channels 128..255.
// ---------------------------------------------------------------------------
__global__ __launch_bounds__(256) void conv1x1(
    const short* __restrict__ attnbuf, const short* __restrict__ Wot,
    float* __restrict__ dout)
{
    const int b    = blockIdx.y;
    const int col0 = blockIdx.x * 32;
    constexpr int RSA = 136;              // row stride (shorts), 16B-aligned

    __shared__ short Wo[16 * 128 * 8];
    __shared__ short As[32 * RSA];        // [col][ci]

    const int t = threadIdx.x;
    {   // Wo: contiguous copy
        short8* dst = (short8*)Wo;
        const short8* src = (const short8*)Wot;
        #pragma unroll
        for (int it = 0; it < 8; ++it) dst[it * 256 + t] = src[it * 256 + t];
    }
    {   // As: transpose 128ci x 32col -> [col][ci]
        const short* ab = attnbuf + b * 128 * 2304;
        #pragma unroll
        for (int it = 0; it < 8; ++it) {
            int e = it * 256 + t;
            int ci = e >> 4, cp = e & 15;
            unsigned v = *(const unsigned*)(ab + ci * 2304 + col0 + cp * 2);
            As[(cp * 2) * RSA + ci]     = (short)(v & 0xffff);
            As[(cp * 2 + 1) * RSA + ci] = (short)(v >> 16);
        }
    }
    __syncthreads();

    const int wave = t >> 6, lane = t & 63, quad = lane >> 4, l16 = lane & 15;
    floatx4 acc[2][2];
    #pragma unroll
    for (int i = 0; i < 2; ++i)
        #pragma unroll
        for (int j = 0; j < 2; ++j) acc[i][j] = (floatx4){0.f, 0.f, 0.f, 0.f};

    #pragma unroll
    for (int kk = 0; kk < 4; ++kk) {
        int chA = kk * 4 + quad;
        short8 a0 = *(const short8*)&Wo[(chA * 128 + wave * 32 + l16) * 8];
        short8 a1 = *(const short8*)&Wo[(chA * 128 + wave * 32 + 16 + l16) * 8];
        #pragma unroll
        for (int nt = 0; nt < 2; ++nt) {
            short8 bf = *(const short8*)&As[(nt * 16 + l16) * RSA + kk * 32 + quad * 8];
            acc[0][nt] = __builtin_amdgcn_mfma_f32_16x16x32_bf16(a0, bf, acc[0][nt], 0, 0, 0);
            acc[1][nt] = __builtin_amdgcn_mfma_f32_16x16x32_bf16(a1, bf, acc[1][nt], 0, 0, 0);
        }
    }

    #pragma unroll
    for (int mt = 0; mt < 2; ++mt)
        #pragma unroll
        for (int nt = 0; nt < 2; ++nt)
            #pragma unroll
            for (int r = 0; r < 4; ++r) {
                int co  = wave * 32 + mt * 16 + quad * 4 + r;
                int col = col0 + nt * 16 + l16;
                dout[(b * 256 + 128 + co) * 2304 + col] = acc[mt][nt][r];  // fp32 out
            }
}

// ---------------------------------------------------------------------------
extern "C" void kernel_launch(void* const* d_in, const int* in_sizes, int n_in,
                              void* d_out, int out_size, void* d_ws, size_t ws_size,
                              hipStream_t stream)
{
    const float* x  = (const float*)d_in[0];
    const float* wi = (const float*)d_in[1];
    const float* wq = (const float*)d_in[2];
    const float* wo = (const float*)d_in[3];
    float* dout = (float*)d_out;

    char* ws = (char*)d_ws;
    short* qkv     = (short*)(ws);                      // 7,077,888 B
    short* attnbuf = (short*)(ws + 7077888);            // 2,359,296 B
    short* Wt      = (short*)(ws + 7077888 + 2359296);  // 1,179,648 B
    short* Wot     = (short*)(ws + 7077888 + 2359296 + 1179648); // 32,768 B

    transform_w<<<2368, 256, 0, stream>>>(wi, wq, wo, Wt, Wot);
    conv_main<<<dim3(48, 4, 4), 256, 0, stream>>>(x, Wt, dout, qkv);
    attn_kernel<<<dim3(36, 32), 256, 0, stream>>>(qkv, attnbuf);
    conv1x1<<<dim3(72, 4), 256, 0, stream>>>(attnbuf, Wot, dout);
}

// Round 4
// 149.536 us; speedup vs baseline: 1.2480x; 1.2480x over previous
//
#include <hip/hip_runtime.h>

typedef __attribute__((ext_vector_type(8))) short short8;
typedef __attribute__((ext_vector_type(4))) float floatx4;

__device__ __forceinline__ short bf16_short(float f) {
    unsigned u = __builtin_bit_cast(unsigned, f);
    u = (u + 0x7fff + ((u >> 16) & 1)) >> 16;   // RNE, finite values only
    return (short)u;
}

__device__ __forceinline__ float fast_exp2(float x) {
#if __has_builtin(__builtin_amdgcn_exp2f)
    return __builtin_amdgcn_exp2f(x);
#else
    return __expf(x * 0.6931471805599453f);
#endif
}

// ---------------------------------------------------------------------------
// Kernel 1: relayout weights (fp32 -> bf16) for MFMA A-fragments.
// Wt layout: [tap(9)][cog(4)][chunk(16)][co(128)][j(8)]  (ci = chunk*8+j)
// Wot layout: [chunk(16)][co(128)][j(8)]
// ---------------------------------------------------------------------------
__global__ __launch_bounds__(256) void transform_w(
    const float* __restrict__ wi, const float* __restrict__ wq,
    const float* __restrict__ wo, short* __restrict__ Wt, short* __restrict__ Wot)
{
    int idx = blockIdx.x * 256 + threadIdx.x;
    if (idx < 589824) {
        int j  = idx & 7;
        int t1 = idx >> 3;
        int co = t1 & 127;
        int t2 = t1 >> 7;
        int chunk = t2 & 15;
        int t3 = t2 >> 4;
        int cog = t3 & 3;
        int tap = t3 >> 2;
        int ci = chunk * 8 + j;
        float v;
        if (cog == 0) v = wi[(co * 128 + ci) * 9 + tap];
        else          v = wq[((((cog - 1) * 128) + co) * 128 + ci) * 9 + tap];
        Wt[idx] = bf16_short(v);
    } else if (idx < 589824 + 16384) {
        int i2 = idx - 589824;
        int j  = i2 & 7;
        int co = (i2 >> 3) & 127;
        int chunk = i2 >> 10;
        int ci = chunk * 8 + j;
        Wot[i2] = bf16_short(wo[co * 128 + ci]);
    }
}

// ---------------------------------------------------------------------------
// Kernel 2: fused circular 3x3 convs (init 128ch + qkv 384ch) as implicit GEMM.
// Block = (y-row, cog, b). M=128 (co group), N=48 (cols of row y), K=1152.
// cog==0 -> d_out (fp32) channels 0..127 ; cog 1..3 -> qkv ws bf16.
// q scaled by 0.25*log2(e) so attention can use exp2 directly.
// W slab for tap t+1 prefetched into registers during tap t's MFMAs.
// ---------------------------------------------------------------------------
__global__ __launch_bounds__(256) void conv_main(
    const float* __restrict__ x, const short* __restrict__ Wt,
    float* __restrict__ dout, short* __restrict__ qkv)
{
    const int y   = blockIdx.x;   // 0..47
    const int cog = blockIdx.y;   // 0..3
    const int b   = blockIdx.z;   // 0..3

    __shared__ short Xs[16 * 3 * 48 * 8];   // [(chunk*3+row)*48+col]*8+j
    __shared__ short Ws[16 * 128 * 8];      // [chunk][co][j]

    const int t = threadIdx.x;

    // Stage X rows y-1,y,y+1 (wrapped): 128ci x 3row x 48col, fp32 -> bf16
    {
        const float* xb = x + b * 128 * 2304;
        #pragma unroll 4
        for (int it = 0; it < 36; ++it) {
            int e   = it * 256 + t;          // 0..9215 column pairs
            int ci  = e / 72;
            int r   = e - ci * 72;
            int row = r / 24;
            int cp  = r - row * 24;
            int rowg = y + row - 1;
            rowg = (rowg < 0) ? rowg + 48 : (rowg >= 48 ? rowg - 48 : rowg);
            float2 v = *(const float2*)(xb + (ci * 48 + rowg) * 48 + cp * 2);
            int slot = ((ci >> 3) * 3 + row) * 48 + cp * 2;
            int j = ci & 7;
            Xs[slot * 8 + j]       = bf16_short(v.x);
            Xs[(slot + 1) * 8 + j] = bf16_short(v.y);
        }
    }

    const int wave = t >> 6, lane = t & 63, quad = lane >> 4, l16 = lane & 15;

    floatx4 acc[2][3];
    #pragma unroll
    for (int i = 0; i < 2; ++i)
        #pragma unroll
        for (int jn = 0; jn < 3; ++jn) acc[i][jn] = (floatx4){0.f, 0.f, 0.f, 0.f};

    // prefetch tap 0 W slab into registers
    short8 wreg[8];
    {
        const short8* src = (const short8*)(Wt + (0 * 4 + cog) * 16384);
        #pragma unroll
        for (int i = 0; i < 8; ++i) wreg[i] = src[i * 256 + t];
    }

    for (int tap = 0; tap < 9; ++tap) {
        __syncthreads();   // prev-tap Ws readers done (also covers X staging at tap 0)
        {
            short8* dst = (short8*)Ws;
            #pragma unroll
            for (int i = 0; i < 8; ++i) dst[i * 256 + t] = wreg[i];
        }
        if (tap < 8) {   // prefetch next tap; completes during this tap's MFMAs
            const short8* src = (const short8*)(Wt + ((tap + 1) * 4 + cog) * 16384);
            #pragma unroll
            for (int i = 0; i < 8; ++i) wreg[i] = src[i * 256 + t];
        }
        __syncthreads();

        const int dy = tap / 3, dx = tap % 3;
        int colw[3];
        #pragma unroll
        for (int nt = 0; nt < 3; ++nt) {
            int c = nt * 16 + l16 + dx - 1;
            c = (c < 0) ? c + 48 : (c >= 48 ? c - 48 : c);
            colw[nt] = c;
        }

        #pragma unroll
        for (int kk = 0; kk < 4; ++kk) {
            int chA = kk * 4 + quad;
            short8 a0 = *(const short8*)&Ws[(chA * 128 + wave * 32 + l16) * 8];
            short8 a1 = *(const short8*)&Ws[(chA * 128 + wave * 32 + 16 + l16) * 8];
            #pragma unroll
            for (int nt = 0; nt < 3; ++nt) {
                short8 bf = *(const short8*)&Xs[((chA * 3 + dy) * 48 + colw[nt]) * 8];
                acc[0][nt] = __builtin_amdgcn_mfma_f32_16x16x32_bf16(a0, bf, acc[0][nt], 0, 0, 0);
                acc[1][nt] = __builtin_amdgcn_mfma_f32_16x16x32_bf16(a1, bf, acc[1][nt], 0, 0, 0);
            }
        }
    }

    // Epilogue: C/D layout col=l16 (spatial), row=quad*4+r (co)
    #pragma unroll
    for (int mt = 0; mt < 2; ++mt)
        #pragma unroll
        for (int nt = 0; nt < 3; ++nt)
            #pragma unroll
            for (int r = 0; r < 4; ++r) {
                int col  = nt * 16 + l16;
                int n    = y * 48 + col;
                int co_l = wave * 32 + mt * 16 + quad * 4 + r;
                float v  = acc[mt][nt][r];
                if (cog == 0) {
                    dout[(b * 256 + co_l) * 2304 + n] = v;            // fp32 out
                } else {
                    int c = (cog - 1) * 128 + co_l;
                    if (c < 128) v *= 0.360673762f;   // 0.25 * log2(e)
                    qkv[(b * 384 + c) * 2304 + n] = bf16_short(v);
                }
            }
}

// ---------------------------------------------------------------------------
// Kernel 3: flash-style attention, chunked. Block = (n-tile of 64, b*8+h).
// K staged in 256-row chunks (reg double-buffered: latency hidden), inner
// 8 subtiles of m=32 are barrier-free (Ps is wave-private; same-wave DS ops
// are in-order). Row sums via ones-MFMA into accS (same C layout as acc).
// Logits arrive in log2 domain (scale folded in conv) -> exp2 directly.
// attnbuf layout (b, h, n, d) flat == raw reshape to (b,128,2304).
// ---------------------------------------------------------------------------
__global__ __launch_bounds__(256) void attn_kernel(
    const short* __restrict__ qkv, short* __restrict__ attnbuf)
{
    const int b  = blockIdx.y >> 3, h = blockIdx.y & 7;
    const int n0 = blockIdx.x * 64;
    constexpr int RS = 40;        // row stride (shorts): d 0..15 data, 16..31 zeros
    constexpr int CHUNK = 256;

    __shared__ short Qs[64 * RS];          // [n][k], k 16..31 zero
    __shared__ short Ks[CHUNK * RS];       // [m][k], k 16..31 zero
    __shared__ short Ps[4][16 * RS];       // per-wave P transform buffer

    const int t = threadIdx.x;
    const int wave = t >> 6, lane = t & 63, quad = lane >> 4, l16 = lane & 15;

    {   // zero Qs + Ks once (covers the k>=16 zero padding; persists across chunks)
        unsigned* z1 = (unsigned*)Qs;
        for (int i = t; i < 64 * RS / 2; i += 256) z1[i] = 0;
        unsigned* z2 = (unsigned*)Ks;
        for (int i = t; i < CHUNK * RS / 2; i += 256) z2[i] = 0;
    }
    __syncthreads();

    const short* qb = qkv + (b * 384 + h * 16) * 2304;
    const short* kb = qkv + (b * 384 + 128 + h * 16) * 2304;
    const short* vb = qkv + (b * 384 + 256 + h * 16) * 2304;

    // stage Q tile (transpose d x 64n -> [n][d]); visible after chunk-0 barrier B
    #pragma unroll
    for (int it = 0; it < 2; ++it) {
        int e = it * 256 + t;              // 0..511
        int d = e >> 5, np = e & 31;
        unsigned v = *(const unsigned*)(qb + d * 2304 + n0 + np * 2);
        Qs[(np * 2) * RS + d]     = (short)(v & 0xffff);
        Qs[(np * 2 + 1) * RS + d] = (short)(v >> 16);
    }

    // prefetch K chunk 0 into registers (thread t <-> row m0+t)
    unsigned short kreg[16];
    #pragma unroll
    for (int d = 0; d < 16; ++d)
        kreg[d] = *(const unsigned short*)(kb + d * 2304 + t);

    const short8 kOnes = {0x3F80, 0x3F80, 0x3F80, 0x3F80,
                          0x3F80, 0x3F80, 0x3F80, 0x3F80};   // bf16 1.0 x8

    floatx4 acc  = {0.f, 0.f, 0.f, 0.f};
    floatx4 accS = {0.f, 0.f, 0.f, 0.f};

    for (int c = 0; c < 9; ++c) {
        const int m0 = c * CHUNK;
        __syncthreads();   // prev chunk's Ks readers done (chunk 0: zero/Q staging done)
        {   // commit prefetched K rows: [m][d] via two b128 writes
            short8 w0, w1;
            #pragma unroll
            for (int d = 0; d < 8; ++d) { w0[d] = (short)kreg[d]; w1[d] = (short)kreg[d + 8]; }
            *(short8*)&Ks[t * RS]     = w0;
            *(short8*)&Ks[t * RS + 8] = w1;
        }
        if (c < 8) {   // prefetch next chunk; completes during this chunk's compute
            #pragma unroll
            for (int d = 0; d < 16; ++d)
                kreg[d] = *(const unsigned short*)(kb + d * 2304 + m0 + CHUNK + t);
        }
        __syncthreads();

        short8 aq = *(const short8*)&Qs[(wave * 16 + l16) * RS + quad * 8];
        short* pw = &Ps[wave][0];

        #pragma unroll
        for (int s = 0; s < 8; ++s) {
            const int mm = s * 32;
            short8 bk0 = *(const short8*)&Ks[(mm + l16) * RS + quad * 8];
            short8 bk1 = *(const short8*)&Ks[(mm + 16 + l16) * RS + quad * 8];
            floatx4 z = {0.f, 0.f, 0.f, 0.f};
            floatx4 s0 = __builtin_amdgcn_mfma_f32_16x16x32_bf16(aq, bk0, z, 0, 0, 0);
            floatx4 s1 = __builtin_amdgcn_mfma_f32_16x16x32_bf16(aq, bk1, z, 0, 0, 0);

            // exp2 (scale pre-folded), round-half-up pack, C->A layout via
            // wave-private LDS (no barrier: same-wave DS ops are in-order)
            #pragma unroll
            for (int r = 0; r < 4; ++r) {
                unsigned p0 = __builtin_bit_cast(unsigned, fast_exp2(s0[r]));
                unsigned p1 = __builtin_bit_cast(unsigned, fast_exp2(s1[r]));
                pw[(quad * 4 + r) * RS + l16]      = (short)((p0 + 0x8000u) >> 16);
                pw[(quad * 4 + r) * RS + 16 + l16] = (short)((p1 + 0x8000u) >> 16);
            }
            short8 pf = *(const short8*)&pw[l16 * RS + quad * 8];
            short8 vf = *(const short8*)(vb + l16 * 2304 + m0 + mm + quad * 8);
            acc  = __builtin_amdgcn_mfma_f32_16x16x32_bf16(pf, vf,    acc,  0, 0, 0);
            accS = __builtin_amdgcn_mfma_f32_16x16x32_bf16(pf, kOnes, accS, 0, 0, 0);
        }
    }

    // normalize: accS[r] = full row sum (same row mapping as acc), any col
    #pragma unroll
    for (int r = 0; r < 4; ++r) {
        int nl = quad * 4 + r;
        float v = acc[r] / accS[r];
        int n = n0 + wave * 16 + nl;
        attnbuf[((b * 8 + h) * 2304 + n) * 16 + l16] = bf16_short(v);
    }
}

// ---------------------------------------------------------------------------
// Kernel 4: 1x1 conv on raw-reshaped attention buffer. M=128, N=32, K=128.
// Writes d_out (fp32) channels 128..255.
// ---------------------------------------------------------------------------
__global__ __launch_bounds__(256) void conv1x1(
    const short* __restrict__ attnbuf, const short* __restrict__ Wot,
    float* __restrict__ dout)
{
    const int b    = blockIdx.y;
    const int col0 = blockIdx.x * 32;
    constexpr int RSA = 136;              // row stride (shorts), 16B-aligned

    __shared__ short Wo[16 * 128 * 8];
    __shared__ short As[32 * RSA];        // [col][ci]

    const int t = threadIdx.x;
    {   // Wo: contiguous copy
        short8* dst = (short8*)Wo;
        const short8* src = (const short8*)Wot;
        #pragma unroll
        for (int it = 0; it < 8; ++it) dst[it * 256 + t] = src[it * 256 + t];
    }
    {   // As: transpose 128ci x 32col -> [col][ci]
        const short* ab = attnbuf + b * 128 * 2304;
        #pragma unroll
        for (int it = 0; it < 8; ++it) {
            int e = it * 256 + t;
            int ci = e >> 4, cp = e & 15;
            unsigned v = *(const unsigned*)(ab + ci * 2304 + col0 + cp * 2);
            As[(cp * 2) * RSA + ci]     = (short)(v & 0xffff);
            As[(cp * 2 + 1) * RSA + ci] = (short)(v >> 16);
        }
    }
    __syncthreads();

    const int wave = t >> 6, lane = t & 63, quad = lane >> 4, l16 = lane & 15;
    floatx4 acc[2][2];
    #pragma unroll
    for (int i = 0; i < 2; ++i)
        #pragma unroll
        for (int j = 0; j < 2; ++j) acc[i][j] = (floatx4){0.f, 0.f, 0.f, 0.f};

    #pragma unroll
    for (int kk = 0; kk < 4; ++kk) {
        int chA = kk * 4 + quad;
        short8 a0 = *(const short8*)&Wo[(chA * 128 + wave * 32 + l16) * 8];
        short8 a1 = *(const short8*)&Wo[(chA * 128 + wave * 32 + 16 + l16) * 8];
        #pragma unroll
        for (int nt = 0; nt < 2; ++nt) {
            short8 bf = *(const short8*)&As[(nt * 16 + l16) * RSA + kk * 32 + quad * 8];
            acc[0][nt] = __builtin_amdgcn_mfma_f32_16x16x32_bf16(a0, bf, acc[0][nt], 0, 0, 0);
            acc[1][nt] = __builtin_amdgcn_mfma_f32_16x16x32_bf16(a1, bf, acc[1][nt], 0, 0, 0);
        }
    }

    #pragma unroll
    for (int mt = 0; mt < 2; ++mt)
        #pragma unroll
        for (int nt = 0; nt < 2; ++nt)
            #pragma unroll
            for (int r = 0; r < 4; ++r) {
                int co  = wave * 32 + mt * 16 + quad * 4 + r;
                int col = col0 + nt * 16 + l16;
                dout[(b * 256 + 128 + co) * 2304 + col] = acc[mt][nt][r];  // fp32 out
            }
}

// ---------------------------------------------------------------------------
extern "C" void kernel_launch(void* const* d_in, const int* in_sizes, int n_in,
                              void* d_out, int out_size, void* d_ws, size_t ws_size,
                              hipStream_t stream)
{
    const float* x  = (const float*)d_in[0];
    const float* wi = (const float*)d_in[1];
    const float* wq = (const float*)d_in[2];
    const float* wo = (const float*)d_in[3];
    float* dout = (float*)d_out;

    char* ws = (char*)d_ws;
    short* qkv     = (short*)(ws);                      // 7,077,888 B
    short* attnbuf = (short*)(ws + 7077888);            // 2,359,296 B
    short* Wt      = (short*)(ws + 7077888 + 2359296);  // 1,179,648 B
    short* Wot     = (short*)(ws + 7077888 + 2359296 + 1179648); // 32,768 B

    transform_w<<<2368, 256, 0, stream>>>(wi, wq, wo, Wt, Wot);
    conv_main<<<dim3(48, 4, 4), 256, 0, stream>>>(x, Wt, dout, qkv);
    attn_kernel<<<dim3(36, 32), 256, 0, stream>>>(qkv, attnbuf);
    conv1x1<<<dim3(72, 4), 256, 0, stream>>>(attnbuf, Wot, dout);
}